// Round 4
// baseline (150.330 us; speedup 1.0000x reference)
//
#include <hip/hip_runtime.h>
#include <hip/hip_bf16.h>

#define B 8
#define N 25200
#define ROW 85
#define NC 80
#define K 2048
#define MAXDET 300
#define NBUCKET 16384
#define CAND_CAP 4096
#define NCHUNK 32   /* K/64 */
#define STILE 64    /* score tile rows */

// ---------------------------------------------------------------------------
// Kernel 1: score/cls per box + global per-batch 16K-bin score histogram.
// (byte-identical behavior to R3)
// ---------------------------------------------------------------------------
__global__ void __launch_bounds__(256)
nms_score_kernel(const float* __restrict__ x,
                 float* __restrict__ scores,
                 int* __restrict__ cls_id,
                 unsigned* __restrict__ hist) {
    int b = blockIdx.y;
    int i0 = blockIdx.x * STILE;
    int rows = N - i0; if (rows > STILE) rows = STILE;
    __shared__ float lx[STILE * ROW];   // 21760 B
    {
        const float4* s4 = (const float4*)(x + ((size_t)b * N + i0) * ROW);
        float4* d4 = (float4*)lx;
        int nv = rows * ROW / 4;        // 1360 or 1020 (both exact)
        for (int k = threadIdx.x; k < nv; k += 256) d4[k] = s4[k];
    }
    __syncthreads();
    int g = threadIdx.x >> 2;          // box in tile
    int q = threadIdx.x & 3;
    if (g >= rows) return;             // uniform across the 4-lane group
    const float* p = lx + g * ROW;
    float obj = p[4];
    float best = -1e30f;
    int bc = 127;
    if (obj > 0.3f) {
        #pragma unroll
        for (int k = 0; k < 20; ++k) {
            int c = q + 4 * k;
            float v = __fmul_rn(p[5 + c], obj);   // exact, no FMA
            if (v > best) { best = v; bc = c; }   // strict >: in-lane first-max
        }
    }
    #pragma unroll
    for (int m = 1; m < 4; m <<= 1) {   // combine: higher v, tie -> smaller class
        float ov = __shfl_xor(best, m, 64);
        int   oc = __shfl_xor(bc, m, 64);
        if (ov > best || (ov == best && oc < bc)) { best = ov; bc = oc; }
    }
    if (q == 0) {
        int i = i0 + g;
        float score = (obj > 0.3f && best > 0.3f) ? best : -1.0f;
        scores[b * N + i] = score;
        cls_id[b * N + i] = (bc == 127) ? 0 : bc;
        if (score > 0.0f) {
            int qb = (int)(__fmul_rn(score, 16384.0f));   // identical to place's mapping
            if (qb > NBUCKET - 1) qb = NBUCKET - 1;
            atomicAdd(&hist[b * NBUCKET + qb], 1u);
        }
    }
}

// ---------------------------------------------------------------------------
// Kernel 2 (scan): descending exclusive scan of the 16K-bin histogram ->
// global bucket-start ranks. gstart[q] = count of elements in buckets > q.
// Identical arithmetic to the previous in-select scan (bit-identical output).
// One lean block per batch.
// ---------------------------------------------------------------------------
__global__ void __launch_bounds__(1024)
nms_scan_kernel(const unsigned* __restrict__ hist,
                unsigned* __restrict__ gstart) {
    __shared__ unsigned wsum[16];
    int b = blockIdx.x;
    int t = threadIdx.x;
    int ln = t & 63, wv = t >> 6;

    unsigned v[16];
    unsigned A4 = (unsigned)(NBUCKET - 16 - t * 16) / 4;   // ascending uint4 base
    {
        const uint4* gh = (const uint4*)(hist + (size_t)b * NBUCKET);
        uint4 u0 = gh[A4 + 0];
        uint4 u1 = gh[A4 + 1];
        uint4 u2 = gh[A4 + 2];
        uint4 u3 = gh[A4 + 3];
        unsigned u[16] = {u0.x,u0.y,u0.z,u0.w, u1.x,u1.y,u1.z,u1.w,
                          u2.x,u2.y,u2.z,u2.w, u3.x,u3.y,u3.z,u3.w};
        #pragma unroll
        for (int k = 0; k < 16; ++k) v[k] = u[15 - k];
    }
    unsigned S = 0;
    #pragma unroll
    for (int k = 0; k < 16; ++k) S += v[k];
    unsigned pref = S;
    #pragma unroll
    for (int o = 1; o < 64; o <<= 1) { unsigned u = __shfl_up(pref, o, 64); if (ln >= o) pref += u; }
    if (ln == 63) wsum[wv] = pref;
    __syncthreads();
    unsigned wbase = 0;
    for (int w = 0; w < wv; ++w) wbase += wsum[w];
    unsigned running = wbase + pref - S;
    {
        unsigned o[16];
        #pragma unroll
        for (int k = 0; k < 16; ++k) { o[15 - k] = running; running += v[k]; }
        uint4* gs = (uint4*)(gstart + (size_t)b * NBUCKET);
        gs[A4 + 0] = make_uint4(o[0],  o[1],  o[2],  o[3]);
        gs[A4 + 1] = make_uint4(o[4],  o[5],  o[6],  o[7]);
        gs[A4 + 2] = make_uint4(o[8],  o[9],  o[10], o[11]);
        gs[A4 + 3] = make_uint4(o[12], o[13], o[14], o[15]);
    }
}

// ---------------------------------------------------------------------------
// Kernel 3 (place): one thread per box, 200 blocks. Counting-sort placement
// with GLOBAL cursors. Arrival order is nondeterministic (it also was within
// the old single-block version); exactness is preserved because the
// per-bucket full-key sort canonicalizes order, and the only
// arrival-dependent element subset (the bucket straddling CAND_CAP=4096)
// lies entirely above rank 2048 and is never read by the K=2048 gather.
// ---------------------------------------------------------------------------
__global__ void __launch_bounds__(1024)
nms_place_kernel(const float* __restrict__ scores,
                 const unsigned* __restrict__ gstart,
                 unsigned* __restrict__ gcur,
                 unsigned long long* __restrict__ gkeys) {
    int b = blockIdx.y;
    int i = blockIdx.x * 1024 + threadIdx.x;
    if (i >= N) return;
    float s = scores[b * N + i];
    if (s > 0.0f) {
        int q = (int)(__fmul_rn(s, 16384.0f));
        if (q > NBUCKET - 1) q = NBUCKET - 1;
        unsigned start = gstart[b * NBUCKET + q];
        if (start < CAND_CAP) {
            unsigned rank = atomicAdd(&gcur[b * NBUCKET + q], 1u);
            unsigned pos = start + rank;
            if (pos < CAND_CAP) {
                gkeys[(size_t)b * CAND_CAP + pos] =
                    ((unsigned long long)__float_as_uint(s) << 32) | (unsigned)(~i);
            }
        }
    }
}

// ---------------------------------------------------------------------------
// Kernel 4 (finish): load keys -> LDS, per-bucket insertion sort (identical
// code/sequence to the old select), gather top-K boxes/cls/shifted/area.
// Lean: 32 KB LDS, no N-scaled passes. Also zeroes this batch's keepbits.
// ---------------------------------------------------------------------------
__global__ void __launch_bounds__(1024)
nms_finish_kernel(const unsigned* __restrict__ gstart,
                  const unsigned* __restrict__ gcur,
                  const unsigned long long* __restrict__ gkeys,
                  const float* __restrict__ x,
                  const int* __restrict__ cls_id,
                  float* __restrict__ top_s,
                  float* __restrict__ boxes,
                  int* __restrict__ clsk,
                  float* __restrict__ shifted,
                  float* __restrict__ area,
                  unsigned long long* __restrict__ keepbits) {
    __shared__ unsigned long long lk[CAND_CAP];   // 32 KB
    int b = blockIdx.x;
    int t = threadIdx.x;

    if (t < NCHUNK) keepbits[b * NCHUNK + t] = 0ULL;
    {
        const unsigned long long* gk = gkeys + (size_t)b * CAND_CAP;
        for (int k = t; k < CAND_CAP; k += 1024) lk[k] = gk[k];
    }
    __syncthreads();

    // per-bucket insertion sort (descending keys), disjoint ranges
    for (int q = t; q < NBUCKET; q += 1024) {
        unsigned start = gstart[b * NBUCKET + q];
        if (start < CAND_CAP) {
            unsigned c = gcur[b * NBUCKET + q];
            unsigned m = c;
            if (m > CAND_CAP - start) m = CAND_CAP - start;
            if (m >= 2) {
                for (unsigned a = start + 1; a < start + m; ++a) {
                    unsigned long long kv = lk[a];
                    unsigned p2 = a;
                    while (p2 > start && lk[p2 - 1] < kv) { lk[p2] = lk[p2 - 1]; --p2; }
                    lk[p2] = kv;
                }
            }
        }
    }
    __syncthreads();

    // gather top-K
    for (int r = t; r < K; r += 1024) {
        unsigned long long key = lk[r];
        float s;
        int idx;
        float x1, y1, x2, y2;
        int c;
        if (key == 0ULL) {
            s = -1.0f; x1 = y1 = x2 = y2 = 0.0f; c = 0;
        } else {
            s = __uint_as_float((unsigned)(key >> 32));
            idx = (int)(~(unsigned)key);
            const float* p = x + ((size_t)b * N + idx) * ROW;
            float cx = p[0], cy = p[1], w = p[2], h = p[3];
            float hx = __fmul_rn(w, 0.5f);
            float hy = __fmul_rn(h, 0.5f);
            x1 = __fsub_rn(cx, hx); y1 = __fsub_rn(cy, hy);
            x2 = __fadd_rn(cx, hx); y2 = __fadd_rn(cy, hy);
            c = cls_id[b * N + idx];
        }
        int o = b * K + r;
        top_s[o] = s;
        boxes[o * 4 + 0] = x1; boxes[o * 4 + 1] = y1;
        boxes[o * 4 + 2] = x2; boxes[o * 4 + 3] = y2;
        clsk[o] = c;
        float sh = __fmul_rn((float)c, 4096.0f);
        float sx1 = __fadd_rn(x1, sh), sy1 = __fadd_rn(y1, sh);
        float sx2 = __fadd_rn(x2, sh), sy2 = __fadd_rn(y2, sh);
        shifted[o * 4 + 0] = sx1; shifted[o * 4 + 1] = sy1;
        shifted[o * 4 + 2] = sx2; shifted[o * 4 + 3] = sy2;
        area[o] = __fmul_rn(__fsub_rn(sx2, sx1), __fsub_rn(sy2, sy1));
    }
}

// ---------------------------------------------------------------------------
// Kernel 5: per-class greedy NMS (640 parallel waves). Cross-class IoU is
// exactly 0 (class shift 4096 >> max coord 720), so the reference's K-long
// sequential scan decomposes exactly into 80 independent per-class scans.
// (byte-identical to R3)
// ---------------------------------------------------------------------------
__global__ void __launch_bounds__(64)
nms_class_kernel(const float* __restrict__ top_s,
                 const int* __restrict__ clsk,
                 const float* __restrict__ shifted,
                 const float* __restrict__ area,
                 unsigned long long* __restrict__ keepbits) {
    int c = blockIdx.x, b = blockIdx.y;
    int t = threadIdx.x;   // 0..63
    unsigned long long below = (t == 0) ? 0ULL : (~0ULL >> (64 - t));

    __shared__ int srank[K];                    // 8 KB
    __shared__ unsigned long long skeep[NCHUNK];

    // ordered compaction: ranks of this class with valid score, rank-ascending
    int n = 0;
    for (int ch = 0; ch < NCHUNK; ++ch) {
        int r = ch * 64 + t;
        bool sel = (clsk[b * K + r] == c) && (top_s[b * K + r] > 0.0f);
        unsigned long long m = __ballot(sel);
        if (sel) srank[n + __popcll(m & below)] = r;
        n += __popcll(m);
    }
    __syncthreads();
    if (n == 0) return;

    if (n <= 64) {
        // fast path: member t lives in lane t's registers
        float x1 = 0.f, y1 = 0.f, x2 = 0.f, y2 = 0.f, ar = 0.f;
        int r = -1;
        if (t < n) {
            r = srank[t];
            const float* sb = shifted + ((size_t)b * K + r) * 4;
            x1 = sb[0]; y1 = sb[1]; x2 = sb[2]; y2 = sb[3];
            ar = area[b * K + r];
        }
        unsigned long long keepw = (n == 64) ? ~0ULL : ((1ULL << n) - 1ULL);
        for (int i = 0; i < n; ++i) {
            if (!((keepw >> i) & 1ULL)) continue;   // uniform
            float bx1 = __shfl(x1, i, 64), by1 = __shfl(y1, i, 64);
            float bx2 = __shfl(x2, i, 64), by2 = __shfl(y2, i, 64);
            float ba  = __shfl(ar, i, 64);
            bool cond = false;
            if (t > i && t < n) {
                float lx = fmaxf(bx1, x1), ly = fmaxf(by1, y1);
                float rx = fminf(bx2, x2), ry = fminf(by2, y2);
                float w = fmaxf(__fsub_rn(rx, lx), 0.0f);
                float h = fmaxf(__fsub_rn(ry, ly), 0.0f);
                float inter = __fmul_rn(w, h);
                float denom = __fadd_rn(__fsub_rn(__fadd_rn(ba, ar), inter), 1e-9f);
                cond = __fdiv_rn(inter, denom) > 0.6f;   // exact ref order
            }
            keepw &= ~__ballot(cond);
        }
        if (t < n && ((keepw >> t) & 1ULL))
            atomicOr(&keepbits[b * NCHUNK + (r >> 6)], 1ULL << (r & 63));
        return;
    }

    // general path (n > 64): LDS keep bits, boxes re-read from global.
    // Correctness-only; unreachable for this data distribution.
    for (int w = t; w < NCHUNK; w += 64) {
        int lo = w * 64;
        unsigned long long vw;
        if (n >= lo + 64)      vw = ~0ULL;
        else if (n <= lo)      vw = 0ULL;
        else                   vw = (1ULL << (n - lo)) - 1ULL;
        skeep[w] = vw;
    }
    __syncthreads();
    for (int i = 0; i < n; ++i) {
        if (!((skeep[i >> 6] >> (i & 63)) & 1ULL)) continue;   // uniform
        int ri = srank[i];
        const float* sbi = shifted + ((size_t)b * K + ri) * 4;
        float bx1 = sbi[0], by1 = sbi[1], bx2 = sbi[2], by2 = sbi[3];
        float ba = area[b * K + ri];
        int jb_hi = (n - 1) >> 6;
        for (int jb2 = (i + 1) >> 6; jb2 <= jb_hi; ++jb2) {
            int j = jb2 * 64 + t;
            bool cond = false;
            if (j > i && j < n) {
                int rj = srank[j];
                const float* sbj = shifted + ((size_t)b * K + rj) * 4;
                float x1 = sbj[0], y1 = sbj[1], x2 = sbj[2], y2 = sbj[3];
                float arj = area[b * K + rj];
                float lx = fmaxf(bx1, x1), ly = fmaxf(by1, y1);
                float rx = fminf(bx2, x2), ry = fminf(by2, y2);
                float w = fmaxf(__fsub_rn(rx, lx), 0.0f);
                float h = fmaxf(__fsub_rn(ry, ly), 0.0f);
                float inter = __fmul_rn(w, h);
                float denom = __fadd_rn(__fsub_rn(__fadd_rn(ba, arj), inter), 1e-9f);
                cond = __fdiv_rn(inter, denom) > 0.6f;
            }
            unsigned long long sup = __ballot(cond);
            if (t == 0) skeep[jb2] &= ~sup;
        }
        __syncthreads();
    }
    for (int j = t; j < n; j += 64) {
        if ((skeep[j >> 6] >> (j & 63)) & 1ULL) {
            int r = srank[j];
            atomicOr(&keepbits[b * NCHUNK + (r >> 6)], 1ULL << (r & 63));
        }
    }
}

// ---------------------------------------------------------------------------
// Kernel 6: output phase. Kept boxes first in rank order, then non-kept in
// rank order; top-300 slots. (byte-identical to R3)
// ---------------------------------------------------------------------------
__global__ void __launch_bounds__(64)
nms_out_kernel(const unsigned long long* __restrict__ keepbits,
               const float* __restrict__ top_s,
               const float* __restrict__ boxes,
               const int* __restrict__ clsk,
               float* __restrict__ out) {
    int b = blockIdx.x;
    int lane = threadIdx.x;
    __shared__ unsigned long long kept[NCHUNK];
    if (lane < NCHUNK) kept[lane] = keepbits[b * NCHUNK + lane];
    __syncthreads();

    int total = 0;
    for (int c = 0; c < NCHUNK; ++c) total += __popcll(kept[c]);

    float* dets  = out + (size_t)b * MAXDET * 6;
    float* flags = out + (size_t)B * MAXDET * 6 + (size_t)b * MAXDET;
    unsigned long long below = (lane == 0) ? 0ULL : (~0ULL >> (64 - lane));
    int kc = 0, nc2 = 0;
    for (int c = 0; c < NCHUNK; ++c) {
        int i = c * 64 + lane;
        unsigned long long m = kept[c];
        bool k = ((m >> lane) & 1ULL) != 0ULL;
        int pc = __popcll(m);
        int slot = k ? (kc + __popcll(m & below))
                     : (total + nc2 + __popcll((~m) & below));
        if (slot < MAXDET) {
            int o = b * K + i;
            dets[slot * 6 + 0] = boxes[o * 4 + 0];
            dets[slot * 6 + 1] = boxes[o * 4 + 1];
            dets[slot * 6 + 2] = boxes[o * 4 + 2];
            dets[slot * 6 + 3] = boxes[o * 4 + 3];
            dets[slot * 6 + 4] = top_s[o];
            dets[slot * 6 + 5] = (float)clsk[o];
            flags[slot] = k ? 1.0f : 0.0f;
        }
        kc += pc;
        nc2 += 64 - pc;
    }
}

// ---------------------------------------------------------------------------
extern "C" void kernel_launch(void* const* d_in, const int* in_sizes, int n_in,
                              void* d_out, int out_size, void* d_ws, size_t ws_size,
                              hipStream_t stream) {
    const float* x = (const float*)d_in[0];
    float* out = (float*)d_out;

    char* ws = (char*)d_ws;
    size_t off = 0;
    auto alloc = [&](size_t bytes) -> void* {
        void* p = ws + off;
        off += bytes;
        off = (off + 255) & ~(size_t)255;
        return p;
    };

    float*    scores = (float*)    alloc((size_t)B * N * 4);
    int*      cls_id = (int*)      alloc((size_t)B * N * 4);
    float*    top_s  = (float*)    alloc((size_t)B * K * 4);
    float*    boxes  = (float*)    alloc((size_t)B * K * 4 * 4);
    int*      clsk   = (int*)      alloc((size_t)B * K * 4);
    float*    shifted= (float*)    alloc((size_t)B * K * 4 * 4);
    float*    area   = (float*)    alloc((size_t)B * K * 4);
    unsigned long long* keepbits = (unsigned long long*) alloc((size_t)B * NCHUNK * 8);
    // contiguous zero-region: hist (512K) + cursors (512K) + keys (256K)
    unsigned* hist   = (unsigned*) alloc((size_t)B * NBUCKET * 4);
    unsigned* gcur   = (unsigned*) alloc((size_t)B * NBUCKET * 4);
    unsigned long long* gkeys = (unsigned long long*) alloc((size_t)B * CAND_CAP * 8);
    unsigned* gstart = (unsigned*) alloc((size_t)B * NBUCKET * 4);   // written by scan, no clear needed
    (void)ws_size; // needs ~4.1 MB

    hipMemsetAsync(hist, 0,
                   (size_t)B * NBUCKET * 4 + (size_t)B * NBUCKET * 4 + (size_t)B * CAND_CAP * 8,
                   stream);
    nms_score_kernel<<<dim3((N + STILE - 1) / STILE, B), 256, 0, stream>>>(x, scores, cls_id, hist);
    nms_scan_kernel<<<B, 1024, 0, stream>>>(hist, gstart);
    nms_place_kernel<<<dim3((N + 1023) / 1024, B), 1024, 0, stream>>>(scores, gstart, gcur, gkeys);
    nms_finish_kernel<<<B, 1024, 0, stream>>>(gstart, gcur, gkeys, x, cls_id,
                                              top_s, boxes, clsk, shifted, area, keepbits);
    nms_class_kernel<<<dim3(NC, B), 64, 0, stream>>>(top_s, clsk, shifted, area, keepbits);
    nms_out_kernel<<<B, 64, 0, stream>>>(keepbits, top_s, boxes, clsk, out);
}

// Round 5
// 142.684 us; speedup vs baseline: 1.0536x; 1.0536x over previous
//
#include <hip/hip_runtime.h>
#include <hip/hip_bf16.h>

#define B 8
#define N 25200
#define ROW 85
#define NC 80
#define K 2048
#define MAXDET 300
#define NBUCKET 16384
#define CAND_CAP 4096
#define NCHUNK 32   /* K/64 */
#define STILE 64    /* score tile rows */

// ---------------------------------------------------------------------------
// Kernel 1: score/cls per box + global per-batch 16K-bin score histogram
// + xyxy boxes4 (bit-identical ops to the old gather's box math).
// ---------------------------------------------------------------------------
__global__ void __launch_bounds__(256)
nms_score_kernel(const float* __restrict__ x,
                 float* __restrict__ scores,
                 int* __restrict__ cls_id,
                 unsigned* __restrict__ hist,
                 float4* __restrict__ boxes4) {
    int b = blockIdx.y;
    int i0 = blockIdx.x * STILE;
    int rows = N - i0; if (rows > STILE) rows = STILE;
    __shared__ float lx[STILE * ROW];   // 21760 B
    {
        const float4* s4 = (const float4*)(x + ((size_t)b * N + i0) * ROW);
        float4* d4 = (float4*)lx;
        int nv = rows * ROW / 4;        // 1360 or 1020 (both exact)
        for (int k = threadIdx.x; k < nv; k += 256) d4[k] = s4[k];
    }
    __syncthreads();
    int g = threadIdx.x >> 2;          // box in tile
    int q = threadIdx.x & 3;
    if (g >= rows) return;             // uniform across the 4-lane group
    const float* p = lx + g * ROW;
    float obj = p[4];
    float best = -1e30f;
    int bc = 127;
    if (obj > 0.3f) {
        #pragma unroll
        for (int k = 0; k < 20; ++k) {
            int c = q + 4 * k;
            float v = __fmul_rn(p[5 + c], obj);   // exact, no FMA
            if (v > best) { best = v; bc = c; }   // strict >: in-lane first-max
        }
    }
    #pragma unroll
    for (int m = 1; m < 4; m <<= 1) {   // combine: higher v, tie -> smaller class
        float ov = __shfl_xor(best, m, 64);
        int   oc = __shfl_xor(bc, m, 64);
        if (ov > best || (ov == best && oc < bc)) { best = ov; bc = oc; }
    }
    if (q == 0) {
        int i = i0 + g;
        float score = (obj > 0.3f && best > 0.3f) ? best : -1.0f;
        scores[b * N + i] = score;
        cls_id[b * N + i] = (bc == 127) ? 0 : bc;
        // xyxy with the exact op sequence the gather used on x directly
        float cx = p[0], cy = p[1], w = p[2], h = p[3];
        float hx = __fmul_rn(w, 0.5f);
        float hy = __fmul_rn(h, 0.5f);
        boxes4[b * N + i] = make_float4(__fsub_rn(cx, hx), __fsub_rn(cy, hy),
                                        __fadd_rn(cx, hx), __fadd_rn(cy, hy));
        if (score > 0.0f) {
            int qb = (int)(__fmul_rn(score, 16384.0f));   // identical to select's mapping
            if (qb > NBUCKET - 1) qb = NBUCKET - 1;
            atomicAdd(&hist[b * NBUCKET + qb], 1u);
        }
    }
}

// ---------------------------------------------------------------------------
// Kernel 2 (select): prebuilt-histogram scan -> counting-sort placement ->
// per-bucket insertion sort -> gather top-K (from boxes4, L2-small) ->
// per-class membership bitmasks (clsmask) for the class kernel.
// 148 KB LDS -> 1 block/CU, 8 blocks. Also zeroes keepbits.
// ---------------------------------------------------------------------------
__global__ void __launch_bounds__(1024, 1)
nms_select_kernel(const float* __restrict__ scores,
                  const float4* __restrict__ boxes4,
                  const int* __restrict__ cls_id,
                  const unsigned* __restrict__ hist,
                  float* __restrict__ top_s,
                  float* __restrict__ boxes,
                  int* __restrict__ clsk,
                  float* __restrict__ shifted,
                  float* __restrict__ area,
                  unsigned long long* __restrict__ keepbits,
                  unsigned long long* __restrict__ gclsmask) {
    __shared__ unsigned loff[NBUCKET];               // 64 KB start ranks
    __shared__ unsigned lcnt16[NBUCKET / 2];         // 32 KB packed cursors
    __shared__ unsigned long long lk[CAND_CAP];      // 32 KB sort keys
    __shared__ unsigned long long lcm[NC * NCHUNK];  // 20 KB class masks
    __shared__ unsigned wsum[16];

    int b = blockIdx.x;
    int t = threadIdx.x;
    int ln = t & 63, wv = t >> 6;
    constexpr int NITER = (N + 1023) / 1024;    // 25

    if (t < NCHUNK) keepbits[b * NCHUNK + t] = 0ULL;

    {   // zero cursors + keys + class masks
        uint4 z = {0u, 0u, 0u, 0u};
        uint4* d2 = (uint4*)lcnt16;
        for (int k = t; k < NBUCKET / 8; k += 1024) d2[k] = z;
    }
    for (int k = t; k < CAND_CAP; k += 1024) lk[k] = 0ULL;
    for (int k = t; k < NC * NCHUNK; k += 1024) lcm[k] = 0ULL;

    // descending exclusive scan of the global histogram:
    // loff[q] = count of elements in buckets > q.
    unsigned v[16];
    unsigned A4 = (unsigned)(NBUCKET - 16 - t * 16) / 4;   // ascending uint4 base
    {
        const uint4* gh = (const uint4*)(hist + (size_t)b * NBUCKET);
        uint4 u0 = gh[A4 + 0];
        uint4 u1 = gh[A4 + 1];
        uint4 u2 = gh[A4 + 2];
        uint4 u3 = gh[A4 + 3];
        unsigned u[16] = {u0.x,u0.y,u0.z,u0.w, u1.x,u1.y,u1.z,u1.w,
                          u2.x,u2.y,u2.z,u2.w, u3.x,u3.y,u3.z,u3.w};
        #pragma unroll
        for (int k = 0; k < 16; ++k) v[k] = u[15 - k];
    }
    unsigned S = 0;
    #pragma unroll
    for (int k = 0; k < 16; ++k) S += v[k];
    unsigned pref = S;
    #pragma unroll
    for (int o = 1; o < 64; o <<= 1) { unsigned u = __shfl_up(pref, o, 64); if (ln >= o) pref += u; }
    if (ln == 63) wsum[wv] = pref;
    __syncthreads();            // also covers the zeroing above
    unsigned wbase = 0;
    for (int w = 0; w < wv; ++w) wbase += wsum[w];
    unsigned running = wbase + pref - S;
    {
        unsigned o[16];
        #pragma unroll
        for (int k = 0; k < 16; ++k) { o[15 - k] = running; running += v[k]; }
        ((uint4*)loff)[A4 + 0] = make_uint4(o[0],  o[1],  o[2],  o[3]);
        ((uint4*)loff)[A4 + 1] = make_uint4(o[4],  o[5],  o[6],  o[7]);
        ((uint4*)loff)[A4 + 2] = make_uint4(o[8],  o[9],  o[10], o[11]);
        ((uint4*)loff)[A4 + 3] = make_uint4(o[12], o[13], o[14], o[15]);
    }
    __syncthreads();

    // placement (counting sort): single N-pass over scores
    float sreg[NITER];
    #pragma unroll
    for (int r = 0; r < NITER; ++r) {
        int i = t + r * 1024;
        sreg[r] = (i < N) ? scores[b * N + i] : -1.0f;
    }
    #pragma unroll
    for (int r = 0; r < NITER; ++r) {
        float s = sreg[r];
        if (s > 0.0f) {
            int i = t + r * 1024;
            int q = (int)(__fmul_rn(s, 16384.0f));
            if (q > NBUCKET - 1) q = NBUCKET - 1;
            unsigned start = loff[q];
            if (start < CAND_CAP) {
                unsigned sh = (q & 1) * 16;
                unsigned old = atomicAdd(&lcnt16[q >> 1], 1u << sh);
                unsigned rank = (old >> sh) & 0xFFFFu;
                unsigned pos = start + rank;
                if (pos < CAND_CAP) {
                    unsigned long long key =
                        ((unsigned long long)__float_as_uint(s) << 32) | (unsigned)(~i);
                    lk[pos] = key;
                }
            }
        }
    }
    __syncthreads();

    // per-bucket insertion sort (descending keys), disjoint ranges
    for (int q = t; q < NBUCKET; q += 1024) {
        unsigned start = loff[q];
        if (start < CAND_CAP) {
            unsigned c = (lcnt16[q >> 1] >> ((q & 1) * 16)) & 0xFFFFu;
            unsigned m = c;
            if (m > CAND_CAP - start) m = CAND_CAP - start;
            if (m >= 2) {
                for (unsigned a = start + 1; a < start + m; ++a) {
                    unsigned long long kv = lk[a];
                    unsigned p2 = a;
                    while (p2 > start && lk[p2 - 1] < kv) { lk[p2] = lk[p2 - 1]; --p2; }
                    lk[p2] = kv;
                }
            }
        }
    }
    __syncthreads();

    // gather top-K (+ build class masks)
    for (int r = t; r < K; r += 1024) {
        unsigned long long key = lk[r];
        float s;
        int idx;
        float x1, y1, x2, y2;
        int c;
        if (key == 0ULL) {
            s = -1.0f; x1 = y1 = x2 = y2 = 0.0f; c = 0;
        } else {
            s = __uint_as_float((unsigned)(key >> 32));
            idx = (int)(~(unsigned)key);
            float4 bb = boxes4[(size_t)b * N + idx];
            x1 = bb.x; y1 = bb.y; x2 = bb.z; y2 = bb.w;
            c = cls_id[b * N + idx];
            atomicOr(&lcm[c * NCHUNK + (r >> 6)], 1ULL << (r & 63));
        }
        int o = b * K + r;
        top_s[o] = s;
        boxes[o * 4 + 0] = x1; boxes[o * 4 + 1] = y1;
        boxes[o * 4 + 2] = x2; boxes[o * 4 + 3] = y2;
        clsk[o] = c;
        float sh = __fmul_rn((float)c, 4096.0f);
        float sx1 = __fadd_rn(x1, sh), sy1 = __fadd_rn(y1, sh);
        float sx2 = __fadd_rn(x2, sh), sy2 = __fadd_rn(y2, sh);
        shifted[o * 4 + 0] = sx1; shifted[o * 4 + 1] = sy1;
        shifted[o * 4 + 2] = sx2; shifted[o * 4 + 3] = sy2;
        area[o] = __fmul_rn(__fsub_rn(sx2, sx1), __fsub_rn(sy2, sy1));
    }
    __syncthreads();
    // export class masks (fully overwritten every iteration)
    for (int k = t; k < NC * NCHUNK; k += 1024)
        gclsmask[(size_t)b * NC * NCHUNK + k] = lcm[k];
}

// ---------------------------------------------------------------------------
// Kernel 3 (class NMS + fused output): 640 blocks (one wave each).
// Compaction now comes from the prebuilt clsmask words (independent
// wave-uniform loads + VALU) instead of 32 chained global-load+ballot steps.
// The last class block per batch (device atomic counter) runs the output
// phase; keepbits are read back with atomicOr(p,0) for cross-XCD coherence.
// ---------------------------------------------------------------------------
__global__ void __launch_bounds__(64)
nms_classout_kernel(const unsigned long long* __restrict__ gclsmask,
                    const float* __restrict__ top_s,
                    const int* __restrict__ clsk,
                    const float* __restrict__ shifted,
                    const float* __restrict__ area,
                    const float* __restrict__ boxes,
                    unsigned long long* __restrict__ keepbits,
                    unsigned* __restrict__ done_ctr,
                    float* __restrict__ out) {
    int c = blockIdx.x, b = blockIdx.y;
    int t = threadIdx.x;   // 0..63
    unsigned long long below = (t == 0) ? 0ULL : (~0ULL >> (64 - t));

    __shared__ int srank[K];                    // 8 KB
    __shared__ unsigned long long skeep[NCHUNK];

    // compaction from mask words: rank-ascending members of class c
    const unsigned long long* cm = gclsmask + ((size_t)b * NC + c) * NCHUNK;
    int n = 0;
    #pragma unroll 4
    for (int ch = 0; ch < NCHUNK; ++ch) {
        unsigned long long m = cm[ch];          // wave-uniform load
        if ((m >> t) & 1ULL) srank[n + __popcll(m & below)] = ch * 64 + t;
        n += __popcll(m);
    }
    __syncthreads();

    if (n > 0 && n <= 64) {
        // fast path: member t lives in lane t's registers
        float x1 = 0.f, y1 = 0.f, x2 = 0.f, y2 = 0.f, ar = 0.f;
        int r = -1;
        if (t < n) {
            r = srank[t];
            const float* sb = shifted + ((size_t)b * K + r) * 4;
            x1 = sb[0]; y1 = sb[1]; x2 = sb[2]; y2 = sb[3];
            ar = area[b * K + r];
        }
        unsigned long long keepw = (n == 64) ? ~0ULL : ((1ULL << n) - 1ULL);
        for (int i = 0; i < n; ++i) {
            if (!((keepw >> i) & 1ULL)) continue;   // uniform
            float bx1 = __shfl(x1, i, 64), by1 = __shfl(y1, i, 64);
            float bx2 = __shfl(x2, i, 64), by2 = __shfl(y2, i, 64);
            float ba  = __shfl(ar, i, 64);
            bool cond = false;
            if (t > i && t < n) {
                float lx = fmaxf(bx1, x1), ly = fmaxf(by1, y1);
                float rx = fminf(bx2, x2), ry = fminf(by2, y2);
                float w = fmaxf(__fsub_rn(rx, lx), 0.0f);
                float h = fmaxf(__fsub_rn(ry, ly), 0.0f);
                float inter = __fmul_rn(w, h);
                float denom = __fadd_rn(__fsub_rn(__fadd_rn(ba, ar), inter), 1e-9f);
                cond = __fdiv_rn(inter, denom) > 0.6f;   // exact ref order
            }
            keepw &= ~__ballot(cond);
        }
        if (t < n && ((keepw >> t) & 1ULL))
            atomicOr(&keepbits[b * NCHUNK + (r >> 6)], 1ULL << (r & 63));
    } else if (n > 64) {
        // general path (n > 64): correctness-only; unreachable for this data.
        for (int w = t; w < NCHUNK; w += 64) {
            int lo = w * 64;
            unsigned long long vw;
            if (n >= lo + 64)      vw = ~0ULL;
            else if (n <= lo)      vw = 0ULL;
            else                   vw = (1ULL << (n - lo)) - 1ULL;
            skeep[w] = vw;
        }
        __syncthreads();
        for (int i = 0; i < n; ++i) {
            if (!((skeep[i >> 6] >> (i & 63)) & 1ULL)) continue;   // uniform
            int ri = srank[i];
            const float* sbi = shifted + ((size_t)b * K + ri) * 4;
            float bx1 = sbi[0], by1 = sbi[1], bx2 = sbi[2], by2 = sbi[3];
            float ba = area[b * K + ri];
            int jb_hi = (n - 1) >> 6;
            for (int jb2 = (i + 1) >> 6; jb2 <= jb_hi; ++jb2) {
                int j = jb2 * 64 + t;
                bool cond = false;
                if (j > i && j < n) {
                    int rj = srank[j];
                    const float* sbj = shifted + ((size_t)b * K + rj) * 4;
                    float x1 = sbj[0], y1 = sbj[1], x2 = sbj[2], y2 = sbj[3];
                    float arj = area[b * K + rj];
                    float lx = fmaxf(bx1, x1), ly = fmaxf(by1, y1);
                    float rx = fminf(bx2, x2), ry = fminf(by2, y2);
                    float w = fmaxf(__fsub_rn(rx, lx), 0.0f);
                    float h = fmaxf(__fsub_rn(ry, ly), 0.0f);
                    float inter = __fmul_rn(w, h);
                    float denom = __fadd_rn(__fsub_rn(__fadd_rn(ba, arj), inter), 1e-9f);
                    cond = __fdiv_rn(inter, denom) > 0.6f;
                }
                unsigned long long sup = __ballot(cond);
                if (t == 0) skeep[jb2] &= ~sup;
            }
            __syncthreads();
        }
        for (int j = t; j < n; j += 64) {
            if ((skeep[j >> 6] >> (j & 63)) & 1ULL) {
                int r = srank[j];
                atomicOr(&keepbits[b * NCHUNK + (r >> 6)], 1ULL << (r & 63));
            }
        }
    }

    // ---- last-finisher output phase ----
    __threadfence();
    unsigned old = 0;
    if (t == 0) old = atomicAdd(&done_ctr[b], 1u);
    old = (unsigned)__shfl((int)old, 0, 64);
    if (old == NC - 1) {
        __threadfence();
        __shared__ unsigned long long kept[NCHUNK];
        if (t < NCHUNK)
            kept[t] = atomicOr(&keepbits[b * NCHUNK + t], 0ULL);   // coherent read
        __syncthreads();

        int total = 0;
        for (int ch = 0; ch < NCHUNK; ++ch) total += __popcll(kept[ch]);

        float* dets  = out + (size_t)b * MAXDET * 6;
        float* flags = out + (size_t)B * MAXDET * 6 + (size_t)b * MAXDET;
        int kc = 0, nc2 = 0;
        for (int ch = 0; ch < NCHUNK; ++ch) {
            int i = ch * 64 + t;
            unsigned long long m = kept[ch];
            bool k = ((m >> t) & 1ULL) != 0ULL;
            int pc = __popcll(m);
            int slot = k ? (kc + __popcll(m & below))
                         : (total + nc2 + __popcll((~m) & below));
            if (slot < MAXDET) {
                int o = b * K + i;
                dets[slot * 6 + 0] = boxes[o * 4 + 0];
                dets[slot * 6 + 1] = boxes[o * 4 + 1];
                dets[slot * 6 + 2] = boxes[o * 4 + 2];
                dets[slot * 6 + 3] = boxes[o * 4 + 3];
                dets[slot * 6 + 4] = top_s[o];
                dets[slot * 6 + 5] = (float)clsk[o];
                flags[slot] = k ? 1.0f : 0.0f;
            }
            kc += pc;
            nc2 += 64 - pc;
        }
    }
}

// ---------------------------------------------------------------------------
extern "C" void kernel_launch(void* const* d_in, const int* in_sizes, int n_in,
                              void* d_out, int out_size, void* d_ws, size_t ws_size,
                              hipStream_t stream) {
    const float* x = (const float*)d_in[0];
    float* out = (float*)d_out;

    char* ws = (char*)d_ws;
    size_t off = 0;
    auto alloc = [&](size_t bytes) -> void* {
        void* p = ws + off;
        off += bytes;
        off = (off + 255) & ~(size_t)255;
        return p;
    };

    float*    scores = (float*)    alloc((size_t)B * N * 4);
    int*      cls_id = (int*)      alloc((size_t)B * N * 4);
    float4*   boxes4 = (float4*)   alloc((size_t)B * N * 16);
    float*    top_s  = (float*)    alloc((size_t)B * K * 4);
    float*    boxes  = (float*)    alloc((size_t)B * K * 4 * 4);
    int*      clsk   = (int*)      alloc((size_t)B * K * 4);
    float*    shifted= (float*)    alloc((size_t)B * K * 4 * 4);
    float*    area   = (float*)    alloc((size_t)B * K * 4);
    unsigned long long* keepbits = (unsigned long long*) alloc((size_t)B * NCHUNK * 8);
    unsigned long long* gclsmask = (unsigned long long*) alloc((size_t)B * NC * NCHUNK * 8);
    // contiguous zero-region: hist (512 KB) + done_ctr (32 B, 256-aligned slot)
    unsigned* hist     = (unsigned*) alloc((size_t)B * NBUCKET * 4);
    unsigned* done_ctr = (unsigned*) alloc(256);
    (void)ws_size; // needs ~6.8 MB

    hipMemsetAsync(hist, 0, (size_t)B * NBUCKET * 4 + 256, stream);
    nms_score_kernel<<<dim3((N + STILE - 1) / STILE, B), 256, 0, stream>>>(
        x, scores, cls_id, hist, boxes4);
    nms_select_kernel<<<B, 1024, 0, stream>>>(scores, boxes4, cls_id, hist,
                                              top_s, boxes, clsk, shifted, area,
                                              keepbits, gclsmask);
    nms_classout_kernel<<<dim3(NC, B), 64, 0, stream>>>(gclsmask, top_s, clsk,
                                                        shifted, area, boxes,
                                                        keepbits, done_ctr, out);
}

// Round 6
// 141.912 us; speedup vs baseline: 1.0593x; 1.0054x over previous
//
#include <hip/hip_runtime.h>

#define B 8
#define N 25200
#define ROW 85
#define NC 80
#define K 2048
#define MAXDET 300
#define NBUCKET 16384
#define CAND_CAP 4096
#define NCHUNK 32   /* K/64 */
#define STILE 64    /* score tile rows */
#define CTR_STRIDE 64   /* u32 stride per batch counter: 256B, no false sharing */

// ---------------------------------------------------------------------------
// Kernel 1: score/cls per box + xyxy boxes4 (bit-identical box math).
// Block (0,b) also zeroes the ready/done counters for kernel 2.
// ---------------------------------------------------------------------------
__global__ void __launch_bounds__(256)
nms_score_kernel(const float* __restrict__ x,
                 float* __restrict__ scores,
                 int* __restrict__ cls_id,
                 float4* __restrict__ boxes4,
                 unsigned* __restrict__ ready,
                 unsigned* __restrict__ done_ctr) {
    int b = blockIdx.y;
    int i0 = blockIdx.x * STILE;
    if (blockIdx.x == 0 && threadIdx.x == 0) {
        ready[b * CTR_STRIDE] = 0u;
        done_ctr[b * CTR_STRIDE] = 0u;
    }
    int rows = N - i0; if (rows > STILE) rows = STILE;
    __shared__ float lx[STILE * ROW];   // 21760 B
    {
        const float4* s4 = (const float4*)(x + ((size_t)b * N + i0) * ROW);
        float4* d4 = (float4*)lx;
        int nv = rows * ROW / 4;        // 1360 or 1020 (both exact)
        for (int k = threadIdx.x; k < nv; k += 256) d4[k] = s4[k];
    }
    __syncthreads();
    int g = threadIdx.x >> 2;          // box in tile
    int q = threadIdx.x & 3;
    if (g >= rows) return;             // uniform across the 4-lane group
    const float* p = lx + g * ROW;
    float obj = p[4];
    float best = -1e30f;
    int bc = 127;
    if (obj > 0.3f) {
        #pragma unroll
        for (int k = 0; k < 20; ++k) {
            int c = q + 4 * k;
            float v = __fmul_rn(p[5 + c], obj);   // exact, no FMA
            if (v > best) { best = v; bc = c; }   // strict >: in-lane first-max
        }
    }
    #pragma unroll
    for (int m = 1; m < 4; m <<= 1) {   // combine: higher v, tie -> smaller class
        float ov = __shfl_xor(best, m, 64);
        int   oc = __shfl_xor(bc, m, 64);
        if (ov > best || (ov == best && oc < bc)) { best = ov; bc = oc; }
    }
    if (q == 0) {
        int i = i0 + g;
        float score = (obj > 0.3f && best > 0.3f) ? best : -1.0f;
        scores[b * N + i] = score;
        cls_id[b * N + i] = (bc == 127) ? 0 : bc;
        float cx = p[0], cy = p[1], w = p[2], h = p[3];
        float hx = __fmul_rn(w, 0.5f);
        float hy = __fmul_rn(h, 0.5f);
        boxes4[b * N + i] = make_float4(__fsub_rn(cx, hx), __fsub_rn(cy, hy),
                                        __fadd_rn(cx, hx), __fadd_rn(cy, hy));
    }
}

// ---------------------------------------------------------------------------
// Kernel 2 (tail): 48 blocks x 1024 threads, two roles.
//   blocks 0..7  : SELECT for batch b (LDS histogram -> scan -> counting sort
//                  -> per-bucket key sort -> gather top-K + class masks), then
//                  release: __syncthreads -> __threadfence -> ready[b]=1.
//   blocks 8..47 : CLASS-NMS, 16 waves each; block (8 + b*5 + grp), wave wv
//                  handles class grp*16+wv of batch b. Spin on ready[b]
//                  (t0 + acquire fence + syncthreads), register-only
//                  compaction from gclsmask, per-wave greedy NMS (exact fp
//                  sequence), keepbits atomicOr; last-finisher wave (done_ctr)
//                  emits dets/flags. Deadlock-free: 48 blocks <= 256 CUs and
//                  spinners never block the producers.
// ---------------------------------------------------------------------------
__global__ void __launch_bounds__(1024, 1)
nms_tail_kernel(const float* __restrict__ scores,
                const float4* __restrict__ boxes4,
                const int* __restrict__ cls_id,
                float* __restrict__ top_s,
                float* __restrict__ boxes,
                int* __restrict__ clsk,
                float* __restrict__ shifted,
                float* __restrict__ area,
                unsigned long long* __restrict__ keepbits,
                unsigned long long* __restrict__ gclsmask,
                unsigned* __restrict__ ready,
                unsigned* __restrict__ done_ctr,
                float* __restrict__ out) {
    __shared__ unsigned loff[NBUCKET];               // 64 KB hist -> start ranks
    __shared__ unsigned lcnt16[NBUCKET / 2];         // 32 KB packed cursors
    __shared__ unsigned long long lk[CAND_CAP];      // 32 KB sort keys
    __shared__ unsigned long long lcm[NC * NCHUNK];  // 20 KB class masks
    __shared__ unsigned wsum[16];

    int bid = blockIdx.x;
    int t = threadIdx.x;
    int ln = t & 63, wv = t >> 6;
    unsigned long long below = (ln == 0) ? 0ULL : (~0ULL >> (64 - ln));

    if (bid < B) {
        // ================= SELECT role =================
        int b = bid;
        constexpr int NITER = (N + 1023) / 1024;    // 25

        if (t < NCHUNK) keepbits[b * NCHUNK + t] = 0ULL;
        {   // zero histogram + cursors + keys + class masks
            uint4 z = {0u, 0u, 0u, 0u};
            uint4* d1 = (uint4*)loff;
            for (int k = t; k < NBUCKET / 4; k += 1024) d1[k] = z;
            uint4* d2 = (uint4*)lcnt16;
            for (int k = t; k < NBUCKET / 8; k += 1024) d2[k] = z;
        }
        for (int k = t; k < CAND_CAP; k += 1024) lk[k] = 0ULL;
        for (int k = t; k < NC * NCHUNK; k += 1024) lcm[k] = 0ULL;
        __syncthreads();

        // histogram pass: single global read, cache scores in registers
        float sreg[NITER];
        #pragma unroll
        for (int r = 0; r < NITER; ++r) {
            int i = t + r * 1024;
            float s = (i < N) ? scores[b * N + i] : -1.0f;
            sreg[r] = s;
            if (s > 0.0f) {
                int q = (int)(__fmul_rn(s, 16384.0f));
                if (q > NBUCKET - 1) q = NBUCKET - 1;
                atomicAdd(&loff[q], 1u);
            }
        }
        __syncthreads();

        // descending exclusive scan in place: loff[q] = count in buckets > q
        unsigned v[16];
        unsigned A4 = (unsigned)(NBUCKET - 16 - t * 16) / 4;   // ascending uint4 base
        {
            uint4 u0 = ((uint4*)loff)[A4 + 0];
            uint4 u1 = ((uint4*)loff)[A4 + 1];
            uint4 u2 = ((uint4*)loff)[A4 + 2];
            uint4 u3 = ((uint4*)loff)[A4 + 3];
            unsigned u[16] = {u0.x,u0.y,u0.z,u0.w, u1.x,u1.y,u1.z,u1.w,
                              u2.x,u2.y,u2.z,u2.w, u3.x,u3.y,u3.z,u3.w};
            #pragma unroll
            for (int k = 0; k < 16; ++k) v[k] = u[15 - k];
        }
        unsigned S = 0;
        #pragma unroll
        for (int k = 0; k < 16; ++k) S += v[k];
        unsigned pref = S;
        #pragma unroll
        for (int o = 1; o < 64; o <<= 1) { unsigned u = __shfl_up(pref, o, 64); if (ln >= o) pref += u; }
        if (ln == 63) wsum[wv] = pref;
        __syncthreads();
        unsigned wbase = 0;
        for (int w = 0; w < wv; ++w) wbase += wsum[w];
        unsigned running = wbase + pref - S;
        {
            unsigned o[16];
            #pragma unroll
            for (int k = 0; k < 16; ++k) { o[15 - k] = running; running += v[k]; }
            ((uint4*)loff)[A4 + 0] = make_uint4(o[0],  o[1],  o[2],  o[3]);
            ((uint4*)loff)[A4 + 1] = make_uint4(o[4],  o[5],  o[6],  o[7]);
            ((uint4*)loff)[A4 + 2] = make_uint4(o[8],  o[9],  o[10], o[11]);
            ((uint4*)loff)[A4 + 3] = make_uint4(o[12], o[13], o[14], o[15]);
        }
        __syncthreads();

        // placement (counting sort) from register-cached scores
        #pragma unroll
        for (int r = 0; r < NITER; ++r) {
            float s = sreg[r];
            if (s > 0.0f) {
                int i = t + r * 1024;
                int q = (int)(__fmul_rn(s, 16384.0f));
                if (q > NBUCKET - 1) q = NBUCKET - 1;
                unsigned start = loff[q];
                if (start < CAND_CAP) {
                    unsigned sh = (q & 1) * 16;
                    unsigned old = atomicAdd(&lcnt16[q >> 1], 1u << sh);
                    unsigned rank = (old >> sh) & 0xFFFFu;
                    unsigned pos = start + rank;
                    if (pos < CAND_CAP) {
                        unsigned long long key =
                            ((unsigned long long)__float_as_uint(s) << 32) | (unsigned)(~i);
                        lk[pos] = key;
                    }
                }
            }
        }
        __syncthreads();

        // per-bucket insertion sort (descending keys), disjoint ranges
        for (int q = t; q < NBUCKET; q += 1024) {
            unsigned start = loff[q];
            if (start < CAND_CAP) {
                unsigned c = (lcnt16[q >> 1] >> ((q & 1) * 16)) & 0xFFFFu;
                unsigned m = c;
                if (m > CAND_CAP - start) m = CAND_CAP - start;
                if (m >= 2) {
                    for (unsigned a = start + 1; a < start + m; ++a) {
                        unsigned long long kv = lk[a];
                        unsigned p2 = a;
                        while (p2 > start && lk[p2 - 1] < kv) { lk[p2] = lk[p2 - 1]; --p2; }
                        lk[p2] = kv;
                    }
                }
            }
        }
        __syncthreads();

        // gather top-K (+ build class masks)
        for (int r = t; r < K; r += 1024) {
            unsigned long long key = lk[r];
            float s;
            int idx;
            float x1, y1, x2, y2;
            int c;
            if (key == 0ULL) {
                s = -1.0f; x1 = y1 = x2 = y2 = 0.0f; c = 0;
            } else {
                s = __uint_as_float((unsigned)(key >> 32));
                idx = (int)(~(unsigned)key);
                float4 bb = boxes4[(size_t)b * N + idx];
                x1 = bb.x; y1 = bb.y; x2 = bb.z; y2 = bb.w;
                c = cls_id[b * N + idx];
                atomicOr(&lcm[c * NCHUNK + (r >> 6)], 1ULL << (r & 63));
            }
            int o = b * K + r;
            top_s[o] = s;
            boxes[o * 4 + 0] = x1; boxes[o * 4 + 1] = y1;
            boxes[o * 4 + 2] = x2; boxes[o * 4 + 3] = y2;
            clsk[o] = c;
            float sh = __fmul_rn((float)c, 4096.0f);
            float sx1 = __fadd_rn(x1, sh), sy1 = __fadd_rn(y1, sh);
            float sx2 = __fadd_rn(x2, sh), sy2 = __fadd_rn(y2, sh);
            shifted[o * 4 + 0] = sx1; shifted[o * 4 + 1] = sy1;
            shifted[o * 4 + 2] = sx2; shifted[o * 4 + 3] = sy2;
            area[o] = __fmul_rn(__fsub_rn(sx2, sx1), __fsub_rn(sy2, sy1));
        }
        __syncthreads();
        // export class masks
        for (int k = t; k < NC * NCHUNK; k += 1024)
            gclsmask[(size_t)b * NC * NCHUNK + k] = lcm[k];
        __syncthreads();
        // release: device-scope fence (L2 writeback) then flag
        if (t == 0) {
            __threadfence();
            atomicExch(&ready[b * CTR_STRIDE], 1u);
        }
        return;
    }

    // ================= CLASS-NMS role =================
    int gid = bid - B;          // 0..39
    int b = gid / 5;
    int grp = gid % 5;
    int c = grp * 16 + wv;      // this wave's class, 0..79

    // acquire: spin on ready[b], invalidate caches, block-wide barrier
    if (t == 0) {
        while (atomicOr(&ready[b * CTR_STRIDE], 0u) == 0u)
            __builtin_amdgcn_s_sleep(8);
        __threadfence();
    }
    __syncthreads();

    // register-only ordered compaction from the class mask:
    // lane ln gets the ln-th member (rank-ascending) of class c.
    const unsigned long long* cm = gclsmask + ((size_t)b * NC + c) * NCHUNK;
    unsigned long long membw = 0ULL;     // general path: lane ch owns chunk ch
    int n = 0, r = -1, ch_i = -1, myk = -1;
    unsigned long long mych = 0ULL;
    for (int ch = 0; ch < NCHUNK; ++ch) {
        unsigned long long m = cm[ch];   // wave-uniform load
        if (ln == ch) membw = m;
        int cnt = __popcll(m);
        if (myk < 0 && ln < n + cnt) { mych = m; myk = ln - n; ch_i = ch; }
        n += cnt;
    }
    if (myk >= 0) {
        unsigned long long mm = mych;
        for (int z = 0; z < myk; ++z) mm &= mm - 1;
        r = ch_i * 64 + __builtin_ctzll(mm);
    }

    if (n > 0 && n <= 64) {
        // fast path: member ln lives in lane ln's registers
        float x1 = 0.f, y1 = 0.f, x2 = 0.f, y2 = 0.f, ar = 0.f;
        if (ln < n) {
            const float* sb = shifted + ((size_t)b * K + r) * 4;
            x1 = sb[0]; y1 = sb[1]; x2 = sb[2]; y2 = sb[3];
            ar = area[b * K + r];
        }
        unsigned long long keepw = (n == 64) ? ~0ULL : ((1ULL << n) - 1ULL);
        for (int i = 0; i < n; ++i) {
            if (!((keepw >> i) & 1ULL)) continue;   // uniform
            float bx1 = __shfl(x1, i, 64), by1 = __shfl(y1, i, 64);
            float bx2 = __shfl(x2, i, 64), by2 = __shfl(y2, i, 64);
            float ba  = __shfl(ar, i, 64);
            bool cond = false;
            if (ln > i && ln < n) {
                float lx = fmaxf(bx1, x1), ly = fmaxf(by1, y1);
                float rx = fminf(bx2, x2), ry = fminf(by2, y2);
                float w = fmaxf(__fsub_rn(rx, lx), 0.0f);
                float h = fmaxf(__fsub_rn(ry, ly), 0.0f);
                float inter = __fmul_rn(w, h);
                float denom = __fadd_rn(__fsub_rn(__fadd_rn(ba, ar), inter), 1e-9f);
                cond = __fdiv_rn(inter, denom) > 0.6f;   // exact ref order
            }
            keepw &= ~__ballot(cond);
        }
        if (ln < n && ((keepw >> ln) & 1ULL))
            atomicOr(&keepbits[b * NCHUNK + (r >> 6)], 1ULL << (r & 63));
    } else if (n > 64) {
        // general path (n > 64): wave-local, register-distributed keep bits.
        // Correctness-only; unreachable for this data distribution.
        unsigned long long keepw2 = membw;
        for (int i = 0; i < K; ++i) {
            int ch = i >> 6;
            unsigned long long mw = __shfl(membw, ch, 64);
            unsigned long long kw = __shfl(keepw2, ch, 64);
            unsigned long long bi = 1ULL << (i & 63);
            if (!(mw & kw & bi)) continue;   // uniform (shfl results uniform)
            const float* sbi = shifted + ((size_t)b * K + i) * 4;
            float bx1 = sbi[0], by1 = sbi[1], bx2 = sbi[2], by2 = sbi[3];
            float ba = area[b * K + i];
            for (int c2 = ch; c2 < NCHUNK; ++c2) {
                int j = c2 * 64 + ln;
                unsigned long long mw2 = __shfl(membw, c2, 64);
                bool cond = false;
                if (j > i && ((mw2 >> ln) & 1ULL)) {
                    const float* sbj = shifted + ((size_t)b * K + j) * 4;
                    float x1 = sbj[0], y1 = sbj[1], x2 = sbj[2], y2 = sbj[3];
                    float arj = area[b * K + j];
                    float lx = fmaxf(bx1, x1), ly = fmaxf(by1, y1);
                    float rx = fminf(bx2, x2), ry = fminf(by2, y2);
                    float w = fmaxf(__fsub_rn(rx, lx), 0.0f);
                    float h = fmaxf(__fsub_rn(ry, ly), 0.0f);
                    float inter = __fmul_rn(w, h);
                    float denom = __fadd_rn(__fsub_rn(__fadd_rn(ba, arj), inter), 1e-9f);
                    cond = __fdiv_rn(inter, denom) > 0.6f;
                }
                unsigned long long sup = __ballot(cond);
                if (ln == c2) keepw2 &= ~sup;
            }
        }
        if (ln < NCHUNK && (keepw2 & membw))
            atomicOr(&keepbits[b * NCHUNK + ln], keepw2 & membw);
    }

    // ---- last-finisher output phase (one wave per batch) ----
    __threadfence();
    unsigned old = 0;
    if (ln == 0) old = atomicAdd(&done_ctr[b * CTR_STRIDE], 1u);
    old = (unsigned)__shfl((int)old, 0, 64);
    if (old == NC - 1) {
        __threadfence();
        // kept bits: lane ch holds chunk ch (register-distributed, no LDS)
        unsigned long long kw = 0ULL;
        if (ln < NCHUNK) kw = atomicOr(&keepbits[b * NCHUNK + ln], 0ULL);
        int total = 0;
        for (int ch = 0; ch < NCHUNK; ++ch) total += __popcll(__shfl(kw, ch, 64));

        float* dets  = out + (size_t)b * MAXDET * 6;
        float* flags = out + (size_t)B * MAXDET * 6 + (size_t)b * MAXDET;
        int kc = 0, nc2 = 0;
        for (int ch = 0; ch < NCHUNK; ++ch) {
            int i = ch * 64 + ln;
            unsigned long long m = __shfl(kw, ch, 64);
            bool k = ((m >> ln) & 1ULL) != 0ULL;
            int pc = __popcll(m);
            int slot = k ? (kc + __popcll(m & below))
                         : (total + nc2 + __popcll((~m) & below));
            if (slot < MAXDET) {
                int o = b * K + i;
                dets[slot * 6 + 0] = boxes[o * 4 + 0];
                dets[slot * 6 + 1] = boxes[o * 4 + 1];
                dets[slot * 6 + 2] = boxes[o * 4 + 2];
                dets[slot * 6 + 3] = boxes[o * 4 + 3];
                dets[slot * 6 + 4] = top_s[o];
                dets[slot * 6 + 5] = (float)clsk[o];
                flags[slot] = k ? 1.0f : 0.0f;
            }
            kc += pc;
            nc2 += 64 - pc;
        }
    }
}

// ---------------------------------------------------------------------------
extern "C" void kernel_launch(void* const* d_in, const int* in_sizes, int n_in,
                              void* d_out, int out_size, void* d_ws, size_t ws_size,
                              hipStream_t stream) {
    const float* x = (const float*)d_in[0];
    float* out = (float*)d_out;

    char* ws = (char*)d_ws;
    size_t off = 0;
    auto alloc = [&](size_t bytes) -> void* {
        void* p = ws + off;
        off += bytes;
        off = (off + 255) & ~(size_t)255;
        return p;
    };

    float*    scores = (float*)    alloc((size_t)B * N * 4);
    int*      cls_id = (int*)      alloc((size_t)B * N * 4);
    float4*   boxes4 = (float4*)   alloc((size_t)B * N * 16);
    float*    top_s  = (float*)    alloc((size_t)B * K * 4);
    float*    boxes  = (float*)    alloc((size_t)B * K * 4 * 4);
    int*      clsk   = (int*)      alloc((size_t)B * K * 4);
    float*    shifted= (float*)    alloc((size_t)B * K * 4 * 4);
    float*    area   = (float*)    alloc((size_t)B * K * 4);
    unsigned long long* keepbits = (unsigned long long*) alloc((size_t)B * NCHUNK * 8);
    unsigned long long* gclsmask = (unsigned long long*) alloc((size_t)B * NC * NCHUNK * 8);
    unsigned* ready    = (unsigned*) alloc((size_t)B * CTR_STRIDE * 4);
    unsigned* done_ctr = (unsigned*) alloc((size_t)B * CTR_STRIDE * 4);
    (void)ws_size; // needs ~6.2 MB

    nms_score_kernel<<<dim3((N + STILE - 1) / STILE, B), 256, 0, stream>>>(
        x, scores, cls_id, boxes4, ready, done_ctr);
    nms_tail_kernel<<<B + 5 * B, 1024, 0, stream>>>(
        scores, boxes4, cls_id, top_s, boxes, clsk, shifted, area,
        keepbits, gclsmask, ready, done_ctr, out);
}